// Round 2
// baseline (284.836 us; speedup 1.0000x reference)
//
#include <hip/hip_runtime.h>

typedef unsigned short u16;
typedef __attribute__((ext_vector_type(8))) short v8s;   // 8 bf16 = 4 VGPRs
typedef __attribute__((ext_vector_type(4))) float v4f;   // MFMA accumulator / float4
typedef __attribute__((ext_vector_type(4))) float f4;

#define HID 128
#define TM  64          // edges per block
#define EFS 392         // EF LDS row stride (bf16 elements): 384 + 8 pad
#define HS  136         // H LDS row stride (bf16): 128 + 8 pad
#define FOS 136         // fp32 out-staging row stride (floats): 128 + 8 -> 2-way-free banks

__device__ __forceinline__ u16 f2b(float f) {            // fp32 -> bf16 RNE
    union { float f; unsigned u; } v; v.f = f;
    unsigned u = v.u;
    u += 0x7fffu + ((u >> 16) & 1u);
    return (u16)(u >> 16);
}

#define MFMA(A, B, C) __builtin_amdgcn_mfma_f32_16x16x32_bf16(A, B, C, 0, 0, 0)

// ---- weight fp32 -> bf16 pre-pass (once per launch, ~0.2 MB total) ----
// ws layout (u16 elems): Wp @0 (16384) | Wc @16384 | W1 @32768 (49152) | W2 @81920
__global__ void cvt_weights(const float* __restrict__ Wp, const float* __restrict__ Wc,
                            const float* __restrict__ W1, const float* __restrict__ W2,
                            u16* __restrict__ dst)
{
    int i = blockIdx.x * 256 + threadIdx.x;   // float4 index, 24576 total
    const float* s; int off;
    if (i < 4096)       { s = Wp; off = 0; }
    else if (i < 8192)  { s = Wc; off = 4096; }
    else if (i < 20480) { s = W1; off = 8192; }
    else                { s = W2; off = 20480; }
    int j = i - off;
    f4 v = ((const f4*)s)[j];
    u16* d = dst + (size_t)i * 4;
    d[0] = f2b(v[0]); d[1] = f2b(v[1]); d[2] = f2b(v[2]); d[3] = f2b(v[3]);
}

__global__ __launch_bounds__(256, 2) void edge_attr_kernel(
    const float* __restrict__ x_src, const float* __restrict__ x_dst,
    const int* __restrict__ ei,
    const u16* __restrict__ wsW,                 // converted weights in d_ws
    const float* __restrict__ bp, const float* __restrict__ bc,
    const float* __restrict__ b1, const float* __restrict__ b2,
    float* __restrict__ out, int E)
{
    __shared__ __align__(16) u16 sEF[TM * EFS];  // 50176 B; later reused as fp32 out staging
    __shared__ __align__(16) u16 sH [TM * HS];   // 17408 B

    const u16* wsWp = wsW;
    const u16* wsWc = wsW + 16384;
    const u16* wsW1 = wsW + 32768;
    const u16* wsW2 = wsW + 81920;

    const int t  = threadIdx.x;
    const int e0 = blockIdx.x * TM;
    const int* ei0 = ei;
    const int* ei1 = ei + E;

    // ---------------- gather fp32 par/cld, convert to bf16, |par-cld| ----------------
    #pragma unroll
    for (int i = 0; i < 4; ++i) {
        int idx = t + i * 256;          // 64 rows x 16 chunks of 8 floats
        int r = idx >> 4;
        int c = (idx & 15) << 3;
        int e = e0 + r; if (e >= E) e = E - 1;
        const f4* ps = (const f4*)(x_src + (size_t)ei0[e] * HID + c);
        const f4* qs = (const f4*)(x_dst + (size_t)ei1[e] * HID + c);
        f4 p0 = ps[0], p1 = ps[1];
        f4 q0 = qs[0], q1 = qs[1];
        v8s pb, qb, db;
        #pragma unroll
        for (int j = 0; j < 4; ++j) {
            pb[j]     = (short)f2b(p0[j]);
            pb[j + 4] = (short)f2b(p1[j]);
            qb[j]     = (short)f2b(q0[j]);
            qb[j + 4] = (short)f2b(q1[j]);
            db[j]     = (short)f2b(fabsf(p0[j] - q0[j]));
            db[j + 4] = (short)f2b(fabsf(p1[j] - q1[j]));
        }
        *(v8s*)&sEF[r * EFS       + c] = pb;
        *(v8s*)&sEF[r * EFS + 128 + c] = qb;
        *(v8s*)&sEF[r * EFS + 256 + c] = db;
    }
    __syncthreads();

    const int lane = t & 63;
    const int ln = lane & 15;   // C-col / A-row within tile
    const int lq = lane >> 4;   // quad: k-base lq*8; C-row base lq*4
    const int n0 = (t >> 6) * 32;   // wave's output-column slice

    // ---------------- stage 1: enc_p / enc_c (K=128) ----------------
    {
        v8s Bp[2][4], Bc[2][4];
        float bpv[2], bcv[2];
        #pragma unroll
        for (int nt = 0; nt < 2; ++nt) {
            int n = n0 + nt * 16 + ln;
            bpv[nt] = bp[n];
            bcv[nt] = bc[n];
            #pragma unroll
            for (int kt = 0; kt < 4; ++kt) {
                Bp[nt][kt] = *(const v8s*)(wsWp + (size_t)n * HID + kt * 32 + lq * 8);
                Bc[nt][kt] = *(const v8s*)(wsWc + (size_t)n * HID + kt * 32 + lq * 8);
            }
        }
        v4f aP[4][2], aC[4][2];
        #pragma unroll
        for (int mt = 0; mt < 4; ++mt)
            #pragma unroll
            for (int nt = 0; nt < 2; ++nt) {
                aP[mt][nt] = (v4f){0.f, 0.f, 0.f, 0.f};
                aC[mt][nt] = (v4f){0.f, 0.f, 0.f, 0.f};
            }
        #pragma unroll
        for (int mt = 0; mt < 4; ++mt) {
            const int rbase = (mt * 16 + ln) * EFS + lq * 8;
            v8s A[4];
            #pragma unroll
            for (int kt = 0; kt < 4; ++kt) A[kt] = *(const v8s*)&sEF[rbase + kt * 32];
            #pragma unroll
            for (int nt = 0; nt < 2; ++nt)
                #pragma unroll
                for (int kt = 0; kt < 4; ++kt) aP[mt][nt] = MFMA(A[kt], Bp[nt][kt], aP[mt][nt]);
            #pragma unroll
            for (int kt = 0; kt < 4; ++kt) A[kt] = *(const v8s*)&sEF[rbase + 128 + kt * 32];
            #pragma unroll
            for (int nt = 0; nt < 2; ++nt)
                #pragma unroll
                for (int kt = 0; kt < 4; ++kt) aC[mt][nt] = MFMA(A[kt], Bc[nt][kt], aC[mt][nt]);
        }
        __syncthreads();   // all waves done reading par/cld before overwrite
        #pragma unroll
        for (int mt = 0; mt < 4; ++mt)
            #pragma unroll
            for (int nt = 0; nt < 2; ++nt)
                #pragma unroll
                for (int rg = 0; rg < 4; ++rg) {
                    int row = mt * 16 + lq * 4 + rg;
                    int col = n0 + nt * 16 + ln;
                    float vp = aP[mt][nt][rg] + bpv[nt];
                    vp = vp > 0.f ? vp : 0.01f * vp;
                    sEF[row * EFS + col] = f2b(vp);
                    float vc = aC[mt][nt][rg] + bcv[nt];
                    vc = vc > 0.f ? vc : 0.01f * vc;
                    sEF[row * EFS + 128 + col] = f2b(vc);
                }
        __syncthreads();
    }

    // ---------------- stage 2: H = relu(EF @ W1^T + b1)  (K=384) ----------------
    {
        float b1v[2];
        #pragma unroll
        for (int nt = 0; nt < 2; ++nt) b1v[nt] = b1[n0 + nt * 16 + ln];
        v4f acc[4][2];
        #pragma unroll
        for (int mt = 0; mt < 4; ++mt)
            #pragma unroll
            for (int nt = 0; nt < 2; ++nt) acc[mt][nt] = (v4f){0.f, 0.f, 0.f, 0.f};
        #pragma unroll
        for (int ktc = 0; ktc < 3; ++ktc) {          // K chunks of 128
            v8s B[2][4];
            #pragma unroll
            for (int nt = 0; nt < 2; ++nt) {
                int n = n0 + nt * 16 + ln;
                #pragma unroll
                for (int k4 = 0; k4 < 4; ++k4)
                    B[nt][k4] = *(const v8s*)(wsW1 + (size_t)n * 384 + ktc * 128 + k4 * 32 + lq * 8);
            }
            #pragma unroll
            for (int mt = 0; mt < 4; ++mt) {
                const int rbase = (mt * 16 + ln) * EFS + ktc * 128 + lq * 8;
                v8s A[4];
                #pragma unroll
                for (int k4 = 0; k4 < 4; ++k4) A[k4] = *(const v8s*)&sEF[rbase + k4 * 32];
                #pragma unroll
                for (int nt = 0; nt < 2; ++nt)
                    #pragma unroll
                    for (int k4 = 0; k4 < 4; ++k4) acc[mt][nt] = MFMA(A[k4], B[nt][k4], acc[mt][nt]);
            }
        }
        #pragma unroll
        for (int mt = 0; mt < 4; ++mt)
            #pragma unroll
            for (int nt = 0; nt < 2; ++nt)
                #pragma unroll
                for (int rg = 0; rg < 4; ++rg) {
                    int row = mt * 16 + lq * 4 + rg;
                    int col = n0 + nt * 16 + ln;
                    float v = acc[mt][nt][rg] + b1v[nt];
                    sH[row * HS + col] = f2b(fmaxf(v, 0.f));
                }
        __syncthreads();   // H ready; also fences last sEF reads before staging reuse
    }

    // ---------------- stage 3: out = H @ W2^T + b2  (K=128) ----------------
    {
        float* sF = (float*)sEF;     // reuse as fp32 staging, 64 x FOS floats (34816 B)
        v8s B2[2][4];
        float b2v[2];
        #pragma unroll
        for (int nt = 0; nt < 2; ++nt) {
            int n = n0 + nt * 16 + ln;
            b2v[nt] = b2[n];
            #pragma unroll
            for (int kt = 0; kt < 4; ++kt)
                B2[nt][kt] = *(const v8s*)(wsW2 + (size_t)n * HID + kt * 32 + lq * 8);
        }
        v4f acc[4][2];
        #pragma unroll
        for (int mt = 0; mt < 4; ++mt)
            #pragma unroll
            for (int nt = 0; nt < 2; ++nt) acc[mt][nt] = (v4f){0.f, 0.f, 0.f, 0.f};
        #pragma unroll
        for (int mt = 0; mt < 4; ++mt) {
            const int rbase = (mt * 16 + ln) * HS + lq * 8;
            v8s A[4];
            #pragma unroll
            for (int kt = 0; kt < 4; ++kt) A[kt] = *(const v8s*)&sH[rbase + kt * 32];
            #pragma unroll
            for (int nt = 0; nt < 2; ++nt)
                #pragma unroll
                for (int kt = 0; kt < 4; ++kt) acc[mt][nt] = MFMA(A[kt], B2[nt][kt], acc[mt][nt]);
        }
        #pragma unroll
        for (int mt = 0; mt < 4; ++mt)
            #pragma unroll
            for (int nt = 0; nt < 2; ++nt)
                #pragma unroll
                for (int rg = 0; rg < 4; ++rg) {
                    int row = mt * 16 + lq * 4 + rg;
                    int col = n0 + nt * 16 + ln;
                    sF[row * FOS + col] = acc[mt][nt][rg] + b2v[nt];
                }
        __syncthreads();
    }

    // ---------------- coalesced fp32 global store (float4) ----------------
    {
        const float* sF = (const float*)sEF;
        #pragma unroll
        for (int i = 0; i < 8; ++i) {
            int idx = t + i * 256;      // 2048 float4 slots: 64 rows x 32 chunks
            int r = idx >> 5;
            int c = (idx & 31) << 2;
            int e = e0 + r;
            if (e < E)
                *(f4*)(out + (size_t)e * HID + c) = *(const f4*)&sF[r * FOS + c];
        }
    }
}

extern "C" void kernel_launch(void* const* d_in, const int* in_sizes, int n_in,
                              void* d_out, int out_size, void* d_ws, size_t ws_size,
                              hipStream_t stream) {
    const float* x_src = (const float*)d_in[0];
    const float* x_dst = (const float*)d_in[1];
    const int*   ei    = (const int*)d_in[2];
    const float* Wp    = (const float*)d_in[3];
    const float* bp    = (const float*)d_in[4];
    const float* Wc    = (const float*)d_in[5];
    const float* bc    = (const float*)d_in[6];
    const float* W1    = (const float*)d_in[7];
    const float* b1    = (const float*)d_in[8];
    const float* W2    = (const float*)d_in[9];
    const float* b2    = (const float*)d_in[10];
    float* out = (float*)d_out;
    u16* wsW = (u16*)d_ws;                    // 98304 u16 = 196608 B

    int E = in_sizes[2] / 2;                  // edge_index is [2, E]

    cvt_weights<<<96, 256, 0, stream>>>(Wp, Wc, W1, W2, wsW);

    int blocks = (E + TM - 1) / TM;
    edge_attr_kernel<<<blocks, 256, 0, stream>>>(
        x_src, x_dst, ei, wsW, bp, bc, b1, b2, out, E);
}